// Round 14
// baseline (178.921 us; speedup 1.0000x reference)
//
#include <hip/hip_runtime.h>
#include <hip/hip_bf16.h>

typedef __attribute__((ext_vector_type(8))) short bf16x8;
typedef __attribute__((ext_vector_type(16))) float f32x16;
typedef __attribute__((ext_vector_type(4))) float f32x4;
typedef __attribute__((ext_vector_type(4))) int i32x4;
typedef __attribute__((ext_vector_type(4))) unsigned int u32x4;
typedef __attribute__((ext_vector_type(2))) unsigned int u32x2;

// HW packed fp32->bf16 RNE convert (round 13: replaced software RNE sequence).
__device__ __forceinline__ unsigned int cvtpk(float lo, float hi) {
    unsigned int r;
    asm("v_cvt_pk_bf16_f32 %0, %1, %2" : "=v"(r) : "v"(lo), "v"(hi));
    return r;
}
// permlane32_swap: D' = {a.lo, b.lo}, S' = {a.hi, b.hi} (T12 primitive).
__device__ __forceinline__ u32x2 perm32(unsigned int a, unsigned int b) {
#if __has_builtin(__builtin_amdgcn_permlane32_swap)
    return __builtin_amdgcn_permlane32_swap(a, b, false, false);
#else
    asm("v_permlane32_swap_b32 %0, %1" : "+v"(a), "+v"(b));
    u32x2 r; r[0] = a; r[1] = b; return r;
#endif
}
__device__ __forceinline__ void swap32f(float v, float& x, float& y) {
    u32x2 r = perm32(__builtin_bit_cast(unsigned int, v),
                     __builtin_bit_cast(unsigned int, v));
    x = __builtin_bit_cast(float, r[0]);
    y = __builtin_bit_cast(float, r[1]);
}
#define MAX4(v, i) fmaxf(fmaxf(v[i], v[(i)+1]), fmaxf(v[(i)+2], v[(i)+3]))
#define SUM4(v, i) ((v[i] + v[(i)+1]) + (v[(i)+2] + v[(i)+3]))

// Round 14: 512-thread blocks, 8 waves x 32 q-rows. Total regs must fit 128
// so HW grants 4 waves/SIMD (m69: wave slots step at VGPR 64/128/256 — the
// old 2-wave structure's ~230-reg state was pinned at 2/SIMD). T15 dropped:
// at 4 waves/SIMD, TLP hides the softmax->PV chain.
__global__ __launch_bounds__(512, 4) void attn_fwd(
    const float* __restrict__ Vg, const float* __restrict__ Kg,
    const float* __restrict__ Qg, const int* __restrict__ Mg,
    float* __restrict__ Og)
{
    constexpr int S = 2048, H = 16, D = 64, SROW = H * D;
    constexpr float CST = 0.03125f * 1.44269504088896f;  // (1/sqrt(1024))·log2(e)

    // 64 KB: K dbuf 16K | VT dbuf 16K | rest free; epilogue reuses all as O^T
    // [256 q][64 d] fp32 (64 KB). 2 blocks/CU -> 128 KB <= 160 KB.
    __shared__ char smem[65536];
    __shared__ int Tf[32];                                   // per-KV-tile mask flags
    unsigned short* Kl  = (unsigned short*)smem;             // [2][64*64] bf16 [kv][d]
    unsigned short* Vt  = (unsigned short*)(smem + 16384);   // [2][64*64] bf16 [d][kv]

    const int tid  = threadIdx.x;
    const int lane = tid & 63;
    const int w    = tid >> 6;    // wave 0..7
    const int c5   = lane & 31;   // fragment row/col index (= this lane's q-row)
    const int hi   = lane >> 5;   // half-wave index

    // T1: bijective XCD swizzle (512 blocks, 8 XCDs, 64 per XCD)
    const int logical = (blockIdx.x & 7) * 64 + (blockIdx.x >> 3);
    const int qb  = logical & 7;          // 8 q-blocks of 256 rows
    const int h   = (logical >> 3) & 15;
    const int b   = logical >> 7;

    const int q0 = qb * 256 + w * 32;     // this wave's 32 q-rows

    const size_t base = ((size_t)b * S * H + h) * D;
    const float* Qp = Qg + base;
    const float* Kp = Kg + base;
    const float* Vp = Vg + base;
    float*       Op = Og + base;
    const int*   Mp = Mg + b * S;

    // ---- per-tile mask flags (once per block; 512 threads x 4 kv) ----
    if (tid < 32) Tf[tid] = 0;
    __syncthreads();
    {
        i32x4 m0 = *(const i32x4*)(Mp + tid * 4);
        int anyz = 0;
#pragma unroll
        for (int j = 0; j < 4; ++j) anyz |= (m0[j] == 0);
        if (anyz) atomicOr(&Tf[tid >> 4], 1);
    }

    // staging coords (512 threads)
    const int kr  = tid >> 3;          // K-stage row 0..63
    const int kc0 = (tid & 7) << 3;    // K-stage col {0,8,...,56}
    const int vk  = (tid & 31) << 1;   // V-stage kv row pair base
    const int vd0 = (tid >> 5) << 2;   // V-stage d base {0,4,...,60}

    // ---- Q fragments (pre-scaled by CST, HW cvt_pk) ----
    bf16x8 qf[4];
#pragma unroll
    for (int kc = 0; kc < 4; ++kc) {
        const float* qr = Qp + (size_t)(q0 + c5) * SROW + kc * 16 + hi * 8;
        f32x4 x = *(const f32x4*)qr;
        f32x4 y = *(const f32x4*)(qr + 4);
        u32x4 u;
        u[0] = cvtpk(x[0] * CST, x[1] * CST);
        u[1] = cvtpk(x[2] * CST, x[3] * CST);
        u[2] = cvtpk(y[0] * CST, y[1] * CST);
        u[3] = cvtpk(y[2] * CST, y[3] * CST);
        qf[kc] = __builtin_bit_cast(bf16x8, u);
    }

    f32x16 oacc[2];
#pragma unroll
    for (int dt = 0; dt < 2; ++dt)
#pragma unroll
        for (int r = 0; r < 16; ++r) oacc[dt][r] = 0.0f;
    float m_run = -INFINITY, l_run = 0.0f;

    f32x4 kstg[2], vstg[2];

    auto STAGE_LOAD = [&](int t) {
        const int k0 = t * 64;
        const float* src = Kp + (size_t)(k0 + kr) * SROW + kc0;
        kstg[0] = *(const f32x4*)(src);
        kstg[1] = *(const f32x4*)(src + 4);
        const float* s0 = Vp + (size_t)(k0 + vk) * SROW + vd0;
        vstg[0] = *(const f32x4*)(s0);
        vstg[1] = *(const f32x4*)(s0 + SROW);
    };

    auto STAGE_WRITE = [&](int buf) {
        u32x4 a;
        a[0] = cvtpk(kstg[0][0], kstg[0][1]);
        a[1] = cvtpk(kstg[0][2], kstg[0][3]);
        a[2] = cvtpk(kstg[1][0], kstg[1][1]);
        a[3] = cvtpk(kstg[1][2], kstg[1][3]);
        char* kb = (char*)(Kl + buf * 4096) + kr * 128;
        *(u32x4*)(kb + ((kc0 * 2) ^ ((kr & 7) << 4))) = a;
        char* vbase = (char*)(Vt + buf * 4096);
#pragma unroll
        for (int j = 0; j < 4; ++j) {
            int d = vd0 + j;
            unsigned int val = cvtpk(vstg[0][j], vstg[1][j]);
            *(unsigned int*)(vbase + d * 128 + ((vk * 2) ^ ((d & 7) << 4))) = val;
        }
    };

    // ---- prologue: tile 0 -> buffer 0 ----
    STAGE_LOAD(0);
    STAGE_WRITE(0);
    __syncthreads();   // also publishes Tf

    for (int t = 0; t < 32; ++t) {
        const int cur = t & 1;
        const int nxt = cur ^ 1;
        const int k0  = t * 64;

        if (t < 31) STAGE_LOAD(t + 1);   // T14: issue early, write after compute

        // ---- swapped QK^T (32x32x16): sacc[tt] r -> S^T[kv=32tt+(r&3)+8(r>>2)+4hi][q=c5]
        f32x16 sacc[2];
#pragma unroll
        for (int tt = 0; tt < 2; ++tt)
#pragma unroll
            for (int r = 0; r < 16; ++r) sacc[tt][r] = 0.0f;

        __builtin_amdgcn_s_setprio(1);
#pragma unroll
        for (int tt = 0; tt < 2; ++tt) {
#pragma unroll
            for (int kc = 0; kc < 4; ++kc) {
                bf16x8 kf = *(const bf16x8*)((char*)(Kl + cur * 4096) +
                            (32 * tt + c5) * 128 + ((kc * 32 + hi * 16) ^ ((c5 & 7) << 4)));
                sacc[tt] = __builtin_amdgcn_mfma_f32_32x32x16_bf16(
                    kf, qf[kc], sacc[tt], 0, 0, 0);
            }
        }
        __builtin_amdgcn_s_setprio(0);

        // ---- mask (rare slow path; block-uniform branch) ----
        if (Tf[t]) {
            const int* mp = Mp + k0;
#pragma unroll
            for (int tt = 0; tt < 2; ++tt)
#pragma unroll
                for (int rc = 0; rc < 4; ++rc) {
                    i32x4 mv = *(const i32x4*)(mp + 32 * tt + 8 * rc + 4 * hi);
#pragma unroll
                    for (int r = 0; r < 4; ++r)
                        if (!mv[r]) sacc[tt][4 * rc + r] = -1e20f;
                }
        }

        // ---- online softmax: tree max + permlane xor-32 ----
        float mA = fmaxf(MAX4(sacc[0], 0), MAX4(sacc[0], 4));
        float mB = fmaxf(MAX4(sacc[0], 8), MAX4(sacc[0], 12));
        float mC = fmaxf(MAX4(sacc[1], 0), MAX4(sacc[1], 4));
        float mD = fmaxf(MAX4(sacc[1], 8), MAX4(sacc[1], 12));
        float mx = fmaxf(fmaxf(mA, mB), fmaxf(mC, mD));
        {
            float x, y;
            swap32f(mx, x, y);
            mx = fmaxf(x, y);
        }

        // T13 defer-max: skip rescale while max growth <= 8
        if (!__all(mx <= m_run + 8.0f)) {
            float mn = fmaxf(m_run, mx);
            float alpha = __builtin_amdgcn_exp2f(m_run - mn);
            m_run = mn;
            l_run *= alpha;
#pragma unroll
            for (int dt = 0; dt < 2; ++dt)
#pragma unroll
                for (int r = 0; r < 16; ++r) oacc[dt][r] *= alpha;
        }

        // p = exp2(lg - m)
#pragma unroll
        for (int tt = 0; tt < 2; ++tt)
#pragma unroll
            for (int r = 0; r < 16; ++r)
                sacc[tt][r] = __builtin_amdgcn_exp2f(sacc[tt][r] - m_run);

        // row sum: pairwise tree + permlane xor-32
        float sm = (SUM4(sacc[0], 0) + SUM4(sacc[0], 4)) +
                   (SUM4(sacc[0], 8) + SUM4(sacc[0], 12)) +
                   ((SUM4(sacc[1], 0) + SUM4(sacc[1], 4)) +
                    (SUM4(sacc[1], 8) + SUM4(sacc[1], 12)));
        {
            float x, y;
            swap32f(sm, x, y);
            sm = x + y;
        }
        l_run += sm;

        // ---- P -> bf16 pack (HW cvt_pk) ----
        unsigned int pk[2][4][2];
#pragma unroll
        for (int tt = 0; tt < 2; ++tt)
#pragma unroll
            for (int rc = 0; rc < 4; ++rc) {
                pk[tt][rc][0] = cvtpk(sacc[tt][4 * rc],     sacc[tt][4 * rc + 1]);
                pk[tt][rc][1] = cvtpk(sacc[tt][4 * rc + 2], sacc[tt][4 * rc + 3]);
            }

        // ---- permlane32_swap exchange -> pa[ks]: B-frag P^T[k][q=c5] ----
        bf16x8 pa[4];
#pragma unroll
        for (int tt = 0; tt < 2; ++tt) {
#pragma unroll
            for (int pr = 0; pr < 2; ++pr) {
                u32x2 sw0 = perm32(pk[tt][2 * pr][0], pk[tt][2 * pr + 1][0]);
                u32x2 sw1 = perm32(pk[tt][2 * pr][1], pk[tt][2 * pr + 1][1]);
                u32x4 pw;
                pw[0] = sw0[0];
                pw[1] = sw1[0];
                pw[2] = sw0[1];
                pw[3] = sw1[1];
                pa[2 * tt + pr] = __builtin_bit_cast(bf16x8, pw);
            }
        }

        // ---- PV (32x32x16): O^T[dout][q] += V^T[dout][kv] . P^T[kv][q] ----
        __builtin_amdgcn_s_setprio(1);
#pragma unroll
        for (int dt = 0; dt < 2; ++dt) {
#pragma unroll
            for (int ks = 0; ks < 4; ++ks) {
                bf16x8 vf = *(const bf16x8*)((char*)(Vt + cur * 4096) +
                            (32 * dt + c5) * 128 + ((ks * 32 + hi * 16) ^ ((c5 & 7) << 4)));
                oacc[dt] = __builtin_amdgcn_mfma_f32_32x32x16_bf16(
                    vf, pa[ks], oacc[dt], 0, 0, 0);
            }
        }
        __builtin_amdgcn_s_setprio(0);

        if (t < 31) STAGE_WRITE(nxt);
        __syncthreads();
    }

    // ---- epilogue: O^T/l -> 64KB LDS transpose (256 rows) -> coalesced store ----
    float rinv = 1.0f / l_run;
    float* OT = (float*)smem;   // [256 q][64 d], 256 B rows, XOR-swizzled
    {
        const int row = w * 32 + c5;   // 0..255
#pragma unroll
        for (int dt = 0; dt < 2; ++dt)
#pragma unroll
            for (int rc = 0; rc < 4; ++rc) {
                f32x4 v;
#pragma unroll
                for (int i = 0; i < 4; ++i) v[i] = oacc[dt][4 * rc + i] * rinv;
                *(f32x4*)((char*)OT + row * 256 +
                          (((32 * dt + 8 * rc + 4 * hi) * 4) ^ ((row & 7) << 4))) = v;
            }
    }
    __syncthreads();
    {
        const int row = tid >> 1;           // 0..255
        const int dh  = (tid & 1) * 32;     // d-half base
        const int qrow = qb * 256 + row;
#pragma unroll
        for (int k = 0; k < 8; ++k) {
            f32x4 v = *(const f32x4*)((char*)OT + row * 256 +
                       ((dh * 4 + 16 * k) ^ ((row & 7) << 4)));
            *(f32x4*)(Op + (size_t)qrow * SROW + dh + 4 * k) = v;
        }
    }
}

extern "C" void kernel_launch(void* const* d_in, const int* in_sizes, int n_in,
                              void* d_out, int out_size, void* d_ws, size_t ws_size,
                              hipStream_t stream) {
    const float* V = (const float*)d_in[0];
    const float* K = (const float*)d_in[1];
    const float* Q = (const float*)d_in[2];
    const int*   M = (const int*)d_in[3];
    float*       O = (float*)d_out;
    // grid: 8 q-blocks x 16 heads x 4 batch = 512 blocks, 512 threads (8 waves)
    attn_fwd<<<dim3(512), dim3(512), 0, stream>>>(V, K, Q, M, O);
}

// Round 15
// 124.184 us; speedup vs baseline: 1.4408x; 1.4408x over previous
//
#include <hip/hip_runtime.h>
#include <hip/hip_bf16.h>

typedef __attribute__((ext_vector_type(8))) short bf16x8;
typedef __attribute__((ext_vector_type(16))) float f32x16;
typedef __attribute__((ext_vector_type(4))) float f32x4;
typedef __attribute__((ext_vector_type(4))) int i32x4;
typedef __attribute__((ext_vector_type(4))) unsigned int u32x4;
typedef __attribute__((ext_vector_type(2))) unsigned int u32x2;

// HW packed fp32->bf16 RNE convert (round 13: replaced software RNE sequence).
__device__ __forceinline__ unsigned int cvtpk(float lo, float hi) {
    unsigned int r;
    asm("v_cvt_pk_bf16_f32 %0, %1, %2" : "=v"(r) : "v"(lo), "v"(hi));
    return r;
}
// permlane32_swap: D' = {a.lo, b.lo}, S' = {a.hi, b.hi} (T12 primitive).
__device__ __forceinline__ u32x2 perm32(unsigned int a, unsigned int b) {
#if __has_builtin(__builtin_amdgcn_permlane32_swap)
    return __builtin_amdgcn_permlane32_swap(a, b, false, false);
#else
    asm("v_permlane32_swap_b32 %0, %1" : "+v"(a), "+v"(b));
    u32x2 r; r[0] = a; r[1] = b; return r;
#endif
}
__device__ __forceinline__ void swap32f(float v, float& x, float& y) {
    u32x2 r = perm32(__builtin_bit_cast(unsigned int, v),
                     __builtin_bit_cast(unsigned int, v));
    x = __builtin_bit_cast(float, r[0]);
    y = __builtin_bit_cast(float, r[1]);
}
#define MAX4(v, i) fmaxf(fmaxf(v[i], v[(i)+1]), fmaxf(v[(i)+2], v[(i)+3]))
#define SUM4(v, i) ((v[i] + v[(i)+1]) + (v[(i)+2] + v[(i)+3]))

// (256,2): 256-VGPR cap. Round 14's 4-wave/SIMD attempt spilled (unified
// VGPR+AGPR budget 128/wave can't hold this structure) — 2 waves/SIMD with
// deep waves is the structural optimum here. QBLK=256 (round 9), kf/vf shared
// across q-halves (round 11), T15 PV-deferral (round 12), HW cvt_pk (round
// 13), lazy mx-swap + deferred l-combine + mid-iteration STAGE_WRITE (round 15).
__global__ __launch_bounds__(256, 2) void attn_fwd(
    const float* __restrict__ Vg, const float* __restrict__ Kg,
    const float* __restrict__ Qg, const int* __restrict__ Mg,
    float* __restrict__ Og)
{
    constexpr int S = 2048, H = 16, D = 64, SROW = H * D;
    constexpr float CST = 0.03125f * 1.44269504088896f;  // (1/sqrt(1024))·log2(e)

    // 41 KB: K dbuf 16K | VT 3-buf 24K | (+Tf). Epilogue reuses first 32K as O^T.
    __shared__ char smem[40960];
    __shared__ int Tf[32];                                   // per-KV-tile mask flags
    unsigned short* Kl  = (unsigned short*)smem;             // [2][64*64] bf16 [kv][d]
    unsigned short* Vt  = (unsigned short*)(smem + 16384);   // [3][64*64] bf16 [d][kv]

    const int tid  = threadIdx.x;
    const int lane = tid & 63;
    const int w    = tid >> 6;
    const int c5   = lane & 31;   // fragment row/col index (= this lane's q-row)
    const int hi   = lane >> 5;   // half-wave index

    // T1: bijective XCD swizzle (512 blocks, 8 XCDs, 64 per XCD)
    const int logical = (blockIdx.x & 7) * 64 + (blockIdx.x >> 3);
    const int qb  = logical & 7;          // 8 q-blocks of 256 rows
    const int h   = (logical >> 3) & 15;
    const int b   = logical >> 7;

    const int q0 = qb * 256 + w * 32;     // + 128*h2 + c5 per half

    const size_t base = ((size_t)b * S * H + h) * D;
    const float* Qp = Qg + base;
    const float* Kp = Kg + base;
    const float* Vp = Vg + base;
    float*       Op = Og + base;
    const int*   Mp = Mg + b * S;

    // ---- per-tile mask flags (once per block) ----
    if (tid < 32) Tf[tid] = 0;
    __syncthreads();
    {
        const int* mp = Mp + tid * 8;
        i32x4 m0 = *(const i32x4*)mp;
        i32x4 m1 = *(const i32x4*)(mp + 4);
        int anyz = 0;
#pragma unroll
        for (int j = 0; j < 4; ++j) anyz |= (m0[j] == 0) | (m1[j] == 0);
        if (anyz) atomicOr(&Tf[tid >> 3], 1);
    }

    // staging coords
    const int kr  = tid >> 2;          // K-stage row 0..63
    const int kc0 = (tid & 3) << 4;    // K-stage col {0,16,32,48}
    const int vk  = (tid & 31) << 1;   // V-stage kv row pair base
    const int vd0 = (tid >> 5) << 3;   // V-stage d base {0..56}

    // ---- Q fragments, both halves, pre-scaled by CST (cvt_pk packed) ----
    bf16x8 qf[2][4];
#pragma unroll
    for (int h2 = 0; h2 < 2; ++h2)
#pragma unroll
        for (int kc = 0; kc < 4; ++kc) {
            const float* qr = Qp + (size_t)(q0 + 128 * h2 + c5) * SROW + kc * 16 + hi * 8;
            f32x4 x = *(const f32x4*)qr;
            f32x4 y = *(const f32x4*)(qr + 4);
            u32x4 u;
            u[0] = cvtpk(x[0] * CST, x[1] * CST);
            u[1] = cvtpk(x[2] * CST, x[3] * CST);
            u[2] = cvtpk(y[0] * CST, y[1] * CST);
            u[3] = cvtpk(y[2] * CST, y[3] * CST);
            qf[h2][kc] = __builtin_bit_cast(bf16x8, u);
        }

    f32x16 oacc[2][2];
#pragma unroll
    for (int h2 = 0; h2 < 2; ++h2)
#pragma unroll
        for (int dt = 0; dt < 2; ++dt)
#pragma unroll
            for (int r = 0; r < 16; ++r) oacc[h2][dt][r] = 0.0f;
    float m_run[2] = {-INFINITY, -INFINITY};
    float l_run[2] = {0.0f, 0.0f};   // lane-local HALF-row sums (combined at epilogue)

    f32x4 kstg[4], vstg[4];
    bf16x8 paP[2][4];   // P fragments of tile t-1 (T15 carry)
    f32x16 sacc[2][2];

    auto STAGE_LOAD = [&](int t) {
        const int k0 = t * 64;
        const float* src = Kp + (size_t)(k0 + kr) * SROW + kc0;
        kstg[0] = *(const f32x4*)(src);
        kstg[1] = *(const f32x4*)(src + 4);
        kstg[2] = *(const f32x4*)(src + 8);
        kstg[3] = *(const f32x4*)(src + 12);
        const float* s0 = Vp + (size_t)(k0 + vk) * SROW + vd0;
        const float* s1 = s0 + SROW;
        vstg[0] = *(const f32x4*)(s0);
        vstg[1] = *(const f32x4*)(s0 + 4);
        vstg[2] = *(const f32x4*)(s1);
        vstg[3] = *(const f32x4*)(s1 + 4);
    };

    auto STAGE_WRITE = [&](int kbuf, int vbuf) {
        u32x4 a0, a1;
        a0[0] = cvtpk(kstg[0][0], kstg[0][1]);
        a0[1] = cvtpk(kstg[0][2], kstg[0][3]);
        a0[2] = cvtpk(kstg[1][0], kstg[1][1]);
        a0[3] = cvtpk(kstg[1][2], kstg[1][3]);
        a1[0] = cvtpk(kstg[2][0], kstg[2][1]);
        a1[1] = cvtpk(kstg[2][2], kstg[2][3]);
        a1[2] = cvtpk(kstg[3][0], kstg[3][1]);
        a1[3] = cvtpk(kstg[3][2], kstg[3][3]);
        char* kb = (char*)(Kl + kbuf * 4096) + kr * 128;
        *(u32x4*)(kb + ((kc0 * 2)      ^ ((kr & 7) << 4))) = a0;
        *(u32x4*)(kb + ((kc0 * 2 + 16) ^ ((kr & 7) << 4))) = a1;
        char* vbase = (char*)(Vt + vbuf * 4096);
#pragma unroll
        for (int j = 0; j < 8; ++j) {
            int d = vd0 + j;
            float lo = (j < 4) ? vstg[0][j] : vstg[1][j - 4];
            float hv = (j < 4) ? vstg[2][j] : vstg[3][j - 4];
            unsigned int val = cvtpk(lo, hv);
            *(unsigned int*)(vbase + d * 128 + ((vk * 2) ^ ((d & 7) << 4))) = val;
        }
    };

    // softmax + P-pack for one q-half (h2 is a literal at both call sites)
    auto SOFTMAX_PACK = [&](int h2) {
        // lane-local tree max (row max deferred to the rare rescale path:
        // __all spans all 64 lanes, so the THR check is valid on half-row maxes)
        float mA = fmaxf(MAX4(sacc[h2][0], 0), MAX4(sacc[h2][0], 4));
        float mB = fmaxf(MAX4(sacc[h2][0], 8), MAX4(sacc[h2][0], 12));
        float mC = fmaxf(MAX4(sacc[h2][1], 0), MAX4(sacc[h2][1], 4));
        float mD = fmaxf(MAX4(sacc[h2][1], 8), MAX4(sacc[h2][1], 12));
        float mx = fmaxf(fmaxf(mA, mB), fmaxf(mC, mD));

        // T13 defer-max: rescale (and the cross-lane max) only when max grows
        if (!__all(mx <= m_run[h2] + 8.0f)) {
            float x, y;
            swap32f(mx, x, y);
            mx = fmaxf(x, y);
            float mn = fmaxf(m_run[h2], mx);
            float alpha = __builtin_amdgcn_exp2f(m_run[h2] - mn);
            m_run[h2] = mn;
            l_run[h2] *= alpha;
#pragma unroll
            for (int dt = 0; dt < 2; ++dt)
#pragma unroll
                for (int r = 0; r < 16; ++r) oacc[h2][dt][r] *= alpha;
        }

        // p = exp2(lg - m)
#pragma unroll
        for (int tt = 0; tt < 2; ++tt)
#pragma unroll
            for (int r = 0; r < 16; ++r)
                sacc[h2][tt][r] = __builtin_amdgcn_exp2f(sacc[h2][tt][r] - m_run[h2]);

        // lane-local half-row sum; cross-lane combine deferred to epilogue
        float sm = (SUM4(sacc[h2][0], 0) + SUM4(sacc[h2][0], 4)) +
                   (SUM4(sacc[h2][0], 8) + SUM4(sacc[h2][0], 12)) +
                   ((SUM4(sacc[h2][1], 0) + SUM4(sacc[h2][1], 4)) +
                    (SUM4(sacc[h2][1], 8) + SUM4(sacc[h2][1], 12)));
        l_run[h2] += sm;

        // P -> bf16 pack (HW cvt_pk)
        unsigned int pk[2][4][2];
#pragma unroll
        for (int tt = 0; tt < 2; ++tt)
#pragma unroll
            for (int rc = 0; rc < 4; ++rc) {
                pk[tt][rc][0] = cvtpk(sacc[h2][tt][4 * rc],     sacc[h2][tt][4 * rc + 1]);
                pk[tt][rc][1] = cvtpk(sacc[h2][tt][4 * rc + 2], sacc[h2][tt][4 * rc + 3]);
            }

        // permlane32_swap exchange -> paP[h2][ks]: B-frag P^T[k][q=c5]
#pragma unroll
        for (int tt = 0; tt < 2; ++tt) {
#pragma unroll
            for (int pr = 0; pr < 2; ++pr) {
                u32x2 sw0 = perm32(pk[tt][2 * pr][0], pk[tt][2 * pr + 1][0]);
                u32x2 sw1 = perm32(pk[tt][2 * pr][1], pk[tt][2 * pr + 1][1]);
                u32x4 pw;
                pw[0] = sw0[0];
                pw[1] = sw1[0];
                pw[2] = sw0[1];
                pw[3] = sw1[1];
                paP[h2][2 * tt + pr] = __builtin_bit_cast(bf16x8, pw);
            }
        }
    };

    // ---- prologue: tile 0 -> K buf 0, V buf 0 ----
    STAGE_LOAD(0);
    STAGE_WRITE(0, 0);
    __syncthreads();   // also publishes Tf

    for (int t = 0; t < 32; ++t) {
        const int cur  = t & 1;
        const int nxt  = cur ^ 1;
        const int vprv = (t + 2) % 3;   // buffer of tile t-1
        const int vnxt = (t + 1) % 3;   // buffer for tile t+1
        const int k0   = t * 64;

        if (t < 31) STAGE_LOAD(t + 1);   // T14: issue ASAP

        // ---- swapped QK^T (32x32x16), kf shared across both q-halves ----
#pragma unroll
        for (int h2 = 0; h2 < 2; ++h2)
#pragma unroll
            for (int tt = 0; tt < 2; ++tt)
#pragma unroll
                for (int r = 0; r < 16; ++r) sacc[h2][tt][r] = 0.0f;

        __builtin_amdgcn_s_setprio(1);
#pragma unroll
        for (int tt = 0; tt < 2; ++tt) {
#pragma unroll
            for (int kc = 0; kc < 4; ++kc) {
                bf16x8 kf = *(const bf16x8*)((char*)(Kl + cur * 4096) +
                            (32 * tt + c5) * 128 + ((kc * 32 + hi * 16) ^ ((c5 & 7) << 4)));
                sacc[0][tt] = __builtin_amdgcn_mfma_f32_32x32x16_bf16(
                    kf, qf[0][kc], sacc[0][tt], 0, 0, 0);
                sacc[1][tt] = __builtin_amdgcn_mfma_f32_32x32x16_bf16(
                    kf, qf[1][kc], sacc[1][tt], 0, 0, 0);
            }
        }
        // ---- T15: PV(t-1) — independent MFMAs, overlap softmax(t) below ----
        if (t > 0) {
#pragma unroll
            for (int dt = 0; dt < 2; ++dt) {
#pragma unroll
                for (int ks = 0; ks < 4; ++ks) {
                    bf16x8 vf = *(const bf16x8*)((char*)(Vt + vprv * 4096) +
                                (32 * dt + c5) * 128 + ((ks * 32 + hi * 16) ^ ((c5 & 7) << 4)));
                    oacc[0][dt] = __builtin_amdgcn_mfma_f32_32x32x16_bf16(
                        vf, paP[0][ks], oacc[0][dt], 0, 0, 0);
                    oacc[1][dt] = __builtin_amdgcn_mfma_f32_32x32x16_bf16(
                        vf, paP[1][ks], oacc[1][dt], 0, 0, 0);
                }
            }
        }
        __builtin_amdgcn_s_setprio(0);

        // ---- mask (rare slow path; block-uniform branch) ----
        if (Tf[t]) {
            const int* mp = Mp + k0;
#pragma unroll
            for (int tt = 0; tt < 2; ++tt)
#pragma unroll
                for (int rc = 0; rc < 4; ++rc) {
                    i32x4 mv = *(const i32x4*)(mp + 32 * tt + 8 * rc + 4 * hi);
#pragma unroll
                    for (int r = 0; r < 4; ++r)
                        if (!mv[r]) {
                            sacc[0][tt][4 * rc + r] = -1e20f;
                            sacc[1][tt][4 * rc + r] = -1e20f;
                        }
                }
        }

        // ---- softmax h2=0; STAGE_WRITE overlaps softmax h2=1; then h2=1 ----
        SOFTMAX_PACK(0);
        if (t < 31) STAGE_WRITE(nxt, vnxt);   // ds_writes drain under h2=1 VALU
        SOFTMAX_PACK(1);

        __syncthreads();
    }

    // ---- final PV(31): tile 31 lives in V buffer 31%3 = 1 ----
    __builtin_amdgcn_s_setprio(1);
#pragma unroll
    for (int dt = 0; dt < 2; ++dt) {
#pragma unroll
        for (int ks = 0; ks < 4; ++ks) {
            bf16x8 vf = *(const bf16x8*)((char*)(Vt + 1 * 4096) +
                        (32 * dt + c5) * 128 + ((ks * 32 + hi * 16) ^ ((c5 & 7) << 4)));
            oacc[0][dt] = __builtin_amdgcn_mfma_f32_32x32x16_bf16(
                vf, paP[0][ks], oacc[0][dt], 0, 0, 0);
            oacc[1][dt] = __builtin_amdgcn_mfma_f32_32x32x16_bf16(
                vf, paP[1][ks], oacc[1][dt], 0, 0, 0);
        }
    }
    __builtin_amdgcn_s_setprio(0);
    __syncthreads();

    // ---- epilogue: combine half-row l, O^T/l -> LDS transpose -> store ----
    float* OT = (float*)smem;   // [128 q][64 d], 256 B rows, XOR-swizzled
#pragma unroll
    for (int h2 = 0; h2 < 2; ++h2) {
        float lx, ly;
        swap32f(l_run[h2], lx, ly);           // deferred cross-lane l combine
        const float rinv = 1.0f / (lx + ly);
        {
            const int row = w * 32 + c5;
#pragma unroll
            for (int dt = 0; dt < 2; ++dt)
#pragma unroll
                for (int rc = 0; rc < 4; ++rc) {
                    f32x4 v;
#pragma unroll
                    for (int i = 0; i < 4; ++i) v[i] = oacc[h2][dt][4 * rc + i] * rinv;
                    *(f32x4*)((char*)OT + row * 256 +
                              (((32 * dt + 8 * rc + 4 * hi) * 4) ^ ((row & 7) << 4))) = v;
                }
        }
        __syncthreads();
        {
            const int row  = tid >> 1;          // 0..127
            const int half = tid & 1;           // d-half
            const int qrow = qb * 256 + h2 * 128 + row;
#pragma unroll
            for (int k = 0; k < 8; ++k) {
                f32x4 v = *(const f32x4*)((char*)OT + row * 256 +
                           ((128 * half + 16 * k) ^ ((row & 7) << 4)));
                *(f32x4*)(Op + (size_t)qrow * SROW + 32 * half + 4 * k) = v;
            }
        }
        if (h2 == 0) __syncthreads();
    }
}

extern "C" void kernel_launch(void* const* d_in, const int* in_sizes, int n_in,
                              void* d_out, int out_size, void* d_ws, size_t ws_size,
                              hipStream_t stream) {
    const float* V = (const float*)d_in[0];
    const float* K = (const float*)d_in[1];
    const float* Q = (const float*)d_in[2];
    const int*   M = (const int*)d_in[3];
    float*       O = (float*)d_out;
    // grid: 8 q-blocks x 16 heads x 4 batch = 512 blocks (exactly 2/CU), 256 threads
    attn_fwd<<<dim3(512), dim3(256), 0, stream>>>(V, K, Q, M, O);
}

// Round 16
// 111.760 us; speedup vs baseline: 1.6009x; 1.1112x over previous
//
#include <hip/hip_runtime.h>
#include <hip/hip_bf16.h>

typedef __attribute__((ext_vector_type(8))) short bf16x8;
typedef __attribute__((ext_vector_type(16))) float f32x16;
typedef __attribute__((ext_vector_type(4))) float f32x4;
typedef __attribute__((ext_vector_type(4))) int i32x4;
typedef __attribute__((ext_vector_type(4))) unsigned int u32x4;
typedef __attribute__((ext_vector_type(2))) unsigned int u32x2;

// HW packed fp32->bf16 RNE convert (round 13: replaced software RNE sequence).
__device__ __forceinline__ unsigned int cvtpk(float lo, float hi) {
    unsigned int r;
    asm("v_cvt_pk_bf16_f32 %0, %1, %2" : "=v"(r) : "v"(lo), "v"(hi));
    return r;
}
// permlane32_swap: D' = {a.lo, b.lo}, S' = {a.hi, b.hi} (T12 primitive).
__device__ __forceinline__ u32x2 perm32(unsigned int a, unsigned int b) {
#if __has_builtin(__builtin_amdgcn_permlane32_swap)
    return __builtin_amdgcn_permlane32_swap(a, b, false, false);
#else
    asm("v_permlane32_swap_b32 %0, %1" : "+v"(a), "+v"(b));
    u32x2 r; r[0] = a; r[1] = b; return r;
#endif
}
__device__ __forceinline__ void swap32f(float v, float& x, float& y) {
    u32x2 r = perm32(__builtin_bit_cast(unsigned int, v),
                     __builtin_bit_cast(unsigned int, v));
    x = __builtin_bit_cast(float, r[0]);
    y = __builtin_bit_cast(float, r[1]);
}
#define MAX4(v, i) fmaxf(fmaxf(v[i], v[(i)+1]), fmaxf(v[(i)+2], v[(i)+3]))
#define SUM4(v, i) ((v[i] + v[(i)+1]) + (v[(i)+2] + v[(i)+3]))

// (256,2): 256-VGPR cap — 128-cap spilled accumulators (round 6); round 14's
// 4-wave/SIMD attempt also spilled (unified VGPR+AGPR budget). Structure =
// round 13 verbatim (115us known-good) + two strictly-work-removing riders:
// lane-local fast-path max and epilogue-deferred l combine (round 16).
// Round 15's STAGE_WRITE move + lambda restructure regressed -> reverted.
__global__ __launch_bounds__(256, 2) void attn_fwd(
    const float* __restrict__ Vg, const float* __restrict__ Kg,
    const float* __restrict__ Qg, const int* __restrict__ Mg,
    float* __restrict__ Og)
{
    constexpr int S = 2048, H = 16, D = 64, SROW = H * D;
    constexpr float CST = 0.03125f * 1.44269504088896f;  // (1/sqrt(1024))·log2(e)

    // 41 KB: K dbuf 16K | VT 3-buf 24K | (+Tf). Epilogue reuses first 32K as O^T.
    __shared__ char smem[40960];
    __shared__ int Tf[32];                                   // per-KV-tile mask flags
    unsigned short* Kl  = (unsigned short*)smem;             // [2][64*64] bf16 [kv][d]
    unsigned short* Vt  = (unsigned short*)(smem + 16384);   // [3][64*64] bf16 [d][kv]

    const int tid  = threadIdx.x;
    const int lane = tid & 63;
    const int w    = tid >> 6;
    const int c5   = lane & 31;   // fragment row/col index (= this lane's q-row)
    const int hi   = lane >> 5;   // half-wave index

    // T1: bijective XCD swizzle (512 blocks, 8 XCDs, 64 per XCD)
    const int logical = (blockIdx.x & 7) * 64 + (blockIdx.x >> 3);
    const int qb  = logical & 7;          // 8 q-blocks of 256 rows
    const int h   = (logical >> 3) & 15;
    const int b   = logical >> 7;

    const int q0 = qb * 256 + w * 32;     // + 128*h2 + c5 per half

    const size_t base = ((size_t)b * S * H + h) * D;
    const float* Qp = Qg + base;
    const float* Kp = Kg + base;
    const float* Vp = Vg + base;
    float*       Op = Og + base;
    const int*   Mp = Mg + b * S;

    // ---- per-tile mask flags (once per block) ----
    if (tid < 32) Tf[tid] = 0;
    __syncthreads();
    {
        const int* mp = Mp + tid * 8;
        i32x4 m0 = *(const i32x4*)mp;
        i32x4 m1 = *(const i32x4*)(mp + 4);
        int anyz = 0;
#pragma unroll
        for (int j = 0; j < 4; ++j) anyz |= (m0[j] == 0) | (m1[j] == 0);
        if (anyz) atomicOr(&Tf[tid >> 3], 1);
    }

    // staging coords
    const int kr  = tid >> 2;          // K-stage row 0..63
    const int kc0 = (tid & 3) << 4;    // K-stage col {0,16,32,48}
    const int vk  = (tid & 31) << 1;   // V-stage kv row pair base
    const int vd0 = (tid >> 5) << 3;   // V-stage d base {0..56}

    // ---- Q fragments, both halves, pre-scaled by CST (cvt_pk packed) ----
    bf16x8 qf[2][4];
#pragma unroll
    for (int h2 = 0; h2 < 2; ++h2)
#pragma unroll
        for (int kc = 0; kc < 4; ++kc) {
            const float* qr = Qp + (size_t)(q0 + 128 * h2 + c5) * SROW + kc * 16 + hi * 8;
            f32x4 x = *(const f32x4*)qr;
            f32x4 y = *(const f32x4*)(qr + 4);
            u32x4 u;
            u[0] = cvtpk(x[0] * CST, x[1] * CST);
            u[1] = cvtpk(x[2] * CST, x[3] * CST);
            u[2] = cvtpk(y[0] * CST, y[1] * CST);
            u[3] = cvtpk(y[2] * CST, y[3] * CST);
            qf[h2][kc] = __builtin_bit_cast(bf16x8, u);
        }

    f32x16 oacc[2][2];
#pragma unroll
    for (int h2 = 0; h2 < 2; ++h2)
#pragma unroll
        for (int dt = 0; dt < 2; ++dt)
#pragma unroll
            for (int r = 0; r < 16; ++r) oacc[h2][dt][r] = 0.0f;
    float m_run[2] = {-INFINITY, -INFINITY};
    float l_run[2] = {0.0f, 0.0f};   // lane-local HALF-row sums (combined at epilogue)

    f32x4 kstg[4], vstg[4];
    bf16x8 paP[2][4];   // P fragments of tile t-1 (T15 carry)

    auto STAGE_LOAD = [&](int t) {
        const int k0 = t * 64;
        const float* src = Kp + (size_t)(k0 + kr) * SROW + kc0;
        kstg[0] = *(const f32x4*)(src);
        kstg[1] = *(const f32x4*)(src + 4);
        kstg[2] = *(const f32x4*)(src + 8);
        kstg[3] = *(const f32x4*)(src + 12);
        const float* s0 = Vp + (size_t)(k0 + vk) * SROW + vd0;
        const float* s1 = s0 + SROW;
        vstg[0] = *(const f32x4*)(s0);
        vstg[1] = *(const f32x4*)(s0 + 4);
        vstg[2] = *(const f32x4*)(s1);
        vstg[3] = *(const f32x4*)(s1 + 4);
    };

    auto STAGE_WRITE = [&](int kbuf, int vbuf) {
        u32x4 a0, a1;
        a0[0] = cvtpk(kstg[0][0], kstg[0][1]);
        a0[1] = cvtpk(kstg[0][2], kstg[0][3]);
        a0[2] = cvtpk(kstg[1][0], kstg[1][1]);
        a0[3] = cvtpk(kstg[1][2], kstg[1][3]);
        a1[0] = cvtpk(kstg[2][0], kstg[2][1]);
        a1[1] = cvtpk(kstg[2][2], kstg[2][3]);
        a1[2] = cvtpk(kstg[3][0], kstg[3][1]);
        a1[3] = cvtpk(kstg[3][2], kstg[3][3]);
        char* kb = (char*)(Kl + kbuf * 4096) + kr * 128;
        *(u32x4*)(kb + ((kc0 * 2)      ^ ((kr & 7) << 4))) = a0;
        *(u32x4*)(kb + ((kc0 * 2 + 16) ^ ((kr & 7) << 4))) = a1;
        char* vbase = (char*)(Vt + vbuf * 4096);
#pragma unroll
        for (int j = 0; j < 8; ++j) {
            int d = vd0 + j;
            float lo = (j < 4) ? vstg[0][j] : vstg[1][j - 4];
            float hv = (j < 4) ? vstg[2][j] : vstg[3][j - 4];
            unsigned int val = cvtpk(lo, hv);
            *(unsigned int*)(vbase + d * 128 + ((vk * 2) ^ ((d & 7) << 4))) = val;
        }
    };

    // ---- prologue: tile 0 -> K buf 0, V buf 0 ----
    STAGE_LOAD(0);
    STAGE_WRITE(0, 0);
    __syncthreads();   // also publishes Tf

    for (int t = 0; t < 32; ++t) {
        const int cur  = t & 1;
        const int nxt  = cur ^ 1;
        const int vprv = (t + 2) % 3;   // buffer of tile t-1
        const int vnxt = (t + 1) % 3;   // buffer for tile t+1
        const int k0   = t * 64;

        if (t < 31) STAGE_LOAD(t + 1);   // T14: issue ASAP; consumed at iter end

        // ---- swapped QK^T (32x32x16), kf shared across both q-halves ----
        f32x16 sacc[2][2];
#pragma unroll
        for (int h2 = 0; h2 < 2; ++h2)
#pragma unroll
            for (int tt = 0; tt < 2; ++tt)
#pragma unroll
                for (int r = 0; r < 16; ++r) sacc[h2][tt][r] = 0.0f;

        __builtin_amdgcn_s_setprio(1);
#pragma unroll
        for (int tt = 0; tt < 2; ++tt) {
#pragma unroll
            for (int kc = 0; kc < 4; ++kc) {
                bf16x8 kf = *(const bf16x8*)((char*)(Kl + cur * 4096) +
                            (32 * tt + c5) * 128 + ((kc * 32 + hi * 16) ^ ((c5 & 7) << 4)));
                sacc[0][tt] = __builtin_amdgcn_mfma_f32_32x32x16_bf16(
                    kf, qf[0][kc], sacc[0][tt], 0, 0, 0);
                sacc[1][tt] = __builtin_amdgcn_mfma_f32_32x32x16_bf16(
                    kf, qf[1][kc], sacc[1][tt], 0, 0, 0);
            }
        }
        // ---- T15: PV(t-1) — independent MFMAs, overlap softmax(t) below ----
        if (t > 0) {
#pragma unroll
            for (int dt = 0; dt < 2; ++dt) {
#pragma unroll
                for (int ks = 0; ks < 4; ++ks) {
                    bf16x8 vf = *(const bf16x8*)((char*)(Vt + vprv * 4096) +
                                (32 * dt + c5) * 128 + ((ks * 32 + hi * 16) ^ ((c5 & 7) << 4)));
                    oacc[0][dt] = __builtin_amdgcn_mfma_f32_32x32x16_bf16(
                        vf, paP[0][ks], oacc[0][dt], 0, 0, 0);
                    oacc[1][dt] = __builtin_amdgcn_mfma_f32_32x32x16_bf16(
                        vf, paP[1][ks], oacc[1][dt], 0, 0, 0);
                }
            }
        }
        __builtin_amdgcn_s_setprio(0);

        // ---- mask (rare slow path; block-uniform branch) ----
        if (Tf[t]) {
            const int* mp = Mp + k0;
#pragma unroll
            for (int tt = 0; tt < 2; ++tt)
#pragma unroll
                for (int rc = 0; rc < 4; ++rc) {
                    i32x4 mv = *(const i32x4*)(mp + 32 * tt + 8 * rc + 4 * hi);
#pragma unroll
                    for (int r = 0; r < 4; ++r)
                        if (!mv[r]) {
                            sacc[0][tt][4 * rc + r] = -1e20f;
                            sacc[1][tt][4 * rc + r] = -1e20f;
                        }
                }
        }

        // ---- softmax + P-pack per half -> paP (overlaps PV(t-1) MFMAs) ----
#pragma unroll
        for (int h2 = 0; h2 < 2; ++h2) {
            // lane-local tree max; cross-lane swap only on the rare rescale
            // path (__all spans all 64 lanes -> THR test on half-row maxes is
            // conservative-correct)
            float mA = fmaxf(MAX4(sacc[h2][0], 0), MAX4(sacc[h2][0], 4));
            float mB = fmaxf(MAX4(sacc[h2][0], 8), MAX4(sacc[h2][0], 12));
            float mC = fmaxf(MAX4(sacc[h2][1], 0), MAX4(sacc[h2][1], 4));
            float mD = fmaxf(MAX4(sacc[h2][1], 8), MAX4(sacc[h2][1], 12));
            float mx = fmaxf(fmaxf(mA, mB), fmaxf(mC, mD));

            // T13 defer-max: skip rescale while max growth <= 8
            if (!__all(mx <= m_run[h2] + 8.0f)) {
                float x, y;
                swap32f(mx, x, y);
                mx = fmaxf(x, y);
                float mn = fmaxf(m_run[h2], mx);
                float alpha = __builtin_amdgcn_exp2f(m_run[h2] - mn);
                m_run[h2] = mn;
                l_run[h2] *= alpha;
#pragma unroll
                for (int dt = 0; dt < 2; ++dt)
#pragma unroll
                    for (int r = 0; r < 16; ++r) oacc[h2][dt][r] *= alpha;
            }

            // p = exp2(lg - m)
#pragma unroll
            for (int tt = 0; tt < 2; ++tt)
#pragma unroll
                for (int r = 0; r < 16; ++r)
                    sacc[h2][tt][r] = __builtin_amdgcn_exp2f(sacc[h2][tt][r] - m_run[h2]);

            // lane-local half-row sum; cross-lane combine deferred to epilogue
            float sm = (SUM4(sacc[h2][0], 0) + SUM4(sacc[h2][0], 4)) +
                       (SUM4(sacc[h2][0], 8) + SUM4(sacc[h2][0], 12)) +
                       ((SUM4(sacc[h2][1], 0) + SUM4(sacc[h2][1], 4)) +
                        (SUM4(sacc[h2][1], 8) + SUM4(sacc[h2][1], 12)));
            l_run[h2] += sm;

            // P -> bf16 pack (HW cvt_pk)
            unsigned int pk[2][4][2];
#pragma unroll
            for (int tt = 0; tt < 2; ++tt)
#pragma unroll
                for (int rc = 0; rc < 4; ++rc) {
                    pk[tt][rc][0] = cvtpk(sacc[h2][tt][4 * rc],     sacc[h2][tt][4 * rc + 1]);
                    pk[tt][rc][1] = cvtpk(sacc[h2][tt][4 * rc + 2], sacc[h2][tt][4 * rc + 3]);
                }

            // permlane32_swap exchange -> paP[h2][ks]: B-frag P^T[k][q=c5]
#pragma unroll
            for (int tt = 0; tt < 2; ++tt) {
#pragma unroll
                for (int pr = 0; pr < 2; ++pr) {
                    u32x2 sw0 = perm32(pk[tt][2 * pr][0], pk[tt][2 * pr + 1][0]);
                    u32x2 sw1 = perm32(pk[tt][2 * pr][1], pk[tt][2 * pr + 1][1]);
                    u32x4 pw;
                    pw[0] = sw0[0];
                    pw[1] = sw1[0];
                    pw[2] = sw0[1];
                    pw[3] = sw1[1];
                    paP[h2][2 * tt + pr] = __builtin_bit_cast(bf16x8, pw);
                }
            }
        }

        // ---- write next tile's staged data (K dbuf, V 3-buf), one barrier ----
        if (t < 31) STAGE_WRITE(nxt, vnxt);
        __syncthreads();
    }

    // ---- final PV(31): tile 31 lives in V buffer 31%3 = 1 ----
    __builtin_amdgcn_s_setprio(1);
#pragma unroll
    for (int dt = 0; dt < 2; ++dt) {
#pragma unroll
        for (int ks = 0; ks < 4; ++ks) {
            bf16x8 vf = *(const bf16x8*)((char*)(Vt + 1 * 4096) +
                        (32 * dt + c5) * 128 + ((ks * 32 + hi * 16) ^ ((c5 & 7) << 4)));
            oacc[0][dt] = __builtin_amdgcn_mfma_f32_32x32x16_bf16(
                vf, paP[0][ks], oacc[0][dt], 0, 0, 0);
            oacc[1][dt] = __builtin_amdgcn_mfma_f32_32x32x16_bf16(
                vf, paP[1][ks], oacc[1][dt], 0, 0, 0);
        }
    }
    __builtin_amdgcn_s_setprio(0);
    __syncthreads();

    // ---- epilogue: combine half-row l, O^T/l -> LDS transpose -> store ----
    float* OT = (float*)smem;   // [128 q][64 d], 256 B rows, XOR-swizzled
#pragma unroll
    for (int h2 = 0; h2 < 2; ++h2) {
        float lx, ly;
        swap32f(l_run[h2], lx, ly);           // deferred cross-lane l combine
        const float rinv = 1.0f / (lx + ly);
        {
            const int row = w * 32 + c5;
#pragma unroll
            for (int dt = 0; dt < 2; ++dt)
#pragma unroll
                for (int rc = 0; rc < 4; ++rc) {
                    f32x4 v;
#pragma unroll
                    for (int i = 0; i < 4; ++i) v[i] = oacc[h2][dt][4 * rc + i] * rinv;
                    *(f32x4*)((char*)OT + row * 256 +
                              (((32 * dt + 8 * rc + 4 * hi) * 4) ^ ((row & 7) << 4))) = v;
                }
        }
        __syncthreads();
        {
            const int row  = tid >> 1;          // 0..127
            const int half = tid & 1;           // d-half
            const int qrow = qb * 256 + h2 * 128 + row;
#pragma unroll
            for (int k = 0; k < 8; ++k) {
                f32x4 v = *(const f32x4*)((char*)OT + row * 256 +
                           ((128 * half + 16 * k) ^ ((row & 7) << 4)));
                *(f32x4*)(Op + (size_t)qrow * SROW + 32 * half + 4 * k) = v;
            }
        }
        if (h2 == 0) __syncthreads();
    }
}

extern "C" void kernel_launch(void* const* d_in, const int* in_sizes, int n_in,
                              void* d_out, int out_size, void* d_ws, size_t ws_size,
                              hipStream_t stream) {
    const float* V = (const float*)d_in[0];
    const float* K = (const float*)d_in[1];
    const float* Q = (const float*)d_in[2];
    const int*   M = (const int*)d_in[3];
    float*       O = (float*)d_out;
    // grid: 8 q-blocks x 16 heads x 4 batch = 512 blocks (exactly 2/CU), 256 threads
    attn_fwd<<<dim3(512), dim3(256), 0, stream>>>(V, K, Q, M, O);
}